// Round 1
// baseline (1779.401 us; speedup 1.0000x reference)
//
#include <hip/hip_runtime.h>
#include <hip/hip_bf16.h>

typedef __bf16 bf16x8 __attribute__((ext_vector_type(8)));
typedef float  f32x4  __attribute__((ext_vector_type(4)));

#define NB   8
#define C    192
#define C3   576
#define HH   224
#define WWID 224
#define PW   7
#define NH   6
#define HD   32
#define PP   49
#define MPAD 64

// LDS leading dims (bf16 elements): 16B-multiple rows, stride%32dw == 4 -> uniform banks for b128
#define XW_LD 200   // 400 B rows
#define QK_LD 392   // 784 B rows
#define VT_LD 72    // 144 B rows
#define PR_LD 72

__global__ void wla_prep(const float* __restrict__ wqkv, const float* __restrict__ wout,
                         const float* __restrict__ relpos,
                         __bf16* __restrict__ wqkv_bf, __bf16* __restrict__ wout_bf,
                         float* __restrict__ bias6) {
  const int n1 = C3 * C, n2 = C * C, n3 = NH * PP * PP;
  for (int i = blockIdx.x * blockDim.x + threadIdx.x; i < n1 + n2 + n3;
       i += gridDim.x * blockDim.x) {
    if (i < n1) {
      wqkv_bf[i] = (__bf16)wqkv[i];
    } else if (i < n1 + n2) {
      wout_bf[i - n1] = (__bf16)wout[i - n1];
    } else {
      int e = i - n1 - n2;
      int h = e / (PP * PP), r = e % (PP * PP);
      int p = r / PP, q = r % PP;
      int di = p / PW - q / PW + (PW - 1);
      int dj = p % PW - q % PW + (PW - 1);
      bias6[e] = relpos[(h * (2 * PW - 1) + di) * (2 * PW - 1) + dj];
    }
  }
}

__global__ __launch_bounds__(512, 2)
void wla_main(const float* __restrict__ x,
              const __bf16* __restrict__ wqkv_bf, const float* __restrict__ bqkv,
              const float* __restrict__ bias6,
              const __bf16* __restrict__ wout_bf, const float* __restrict__ bout,
              float* __restrict__ out) {
  // 25600 + 50176 + 27648 + 18432 = 121856 B LDS
  __shared__ __align__(16) __bf16 xw[MPAD * XW_LD];   // window input; later attn-out
  __shared__ __align__(16) __bf16 qk[MPAD * QK_LD];   // q cols [0,192), k cols [192,384)
  __shared__ __align__(16) __bf16 vt[NH * HD * VT_LD];// v transposed: [h][dim][token]
  __shared__ __align__(16) __bf16 pr[8 * 16 * PR_LD]; // per-wave probs tile [16][64]

  const int tid  = threadIdx.x;
  const int lane = tid & 63;
  const int wv   = tid >> 6;    // wave 0..7
  const int l15  = lane & 15;
  const int lg   = lane >> 4;   // 0..3

  const int blk = blockIdx.x;
  const int bb  = blk >> 10;        // batch
  const int wi  = blk & 1023;       // window
  const int wy  = wi >> 5, wx = wi & 31;

  const float* xbase = x + (size_t)bb * C * HH * WWID + (size_t)(wy * PW) * WWID + wx * PW;

  // ---- phase 1: stage window into LDS as bf16, zero pad rows 49..63 ----
  for (int e = tid; e < C * PP; e += 512) {
    int c = e / PP, pos = e - c * PP;
    int py = pos / PW, px = pos - py * PW;
    xw[pos * XW_LD + c] = (__bf16)xbase[(size_t)c * HH * WWID + py * WWID + px];
  }
  for (int e = tid; e < (MPAD - PP) * C; e += 512) {
    int rr = e / C, c = e - rr * C;
    xw[(PP + rr) * XW_LD + c] = (__bf16)0.f;
  }
  __syncthreads();

  // ---- phase 2: GEMM1  qkv = xw @ wqkv^T + b_qkv  (M=64, N=576, K=192) ----
  {
    f32x4 acc[5][4];
#pragma unroll
    for (int j = 0; j < 5; ++j)
#pragma unroll
      for (int m = 0; m < 4; ++m) acc[j][m] = (f32x4){0.f, 0.f, 0.f, 0.f};

#pragma unroll
    for (int ks = 0; ks < 6; ++ks) {
      bf16x8 af[4];
#pragma unroll
      for (int m = 0; m < 4; ++m)
        af[m] = *(const bf16x8*)(&xw[(m * 16 + l15) * XW_LD + ks * 32 + lg * 8]);
#pragma unroll
      for (int j = 0; j < 5; ++j) {
        int nt = wv + 8 * j;  // nt>=36 on j==4 for waves>=4: reads land in wout_bf, discarded
        bf16x8 bfr = *(const bf16x8*)(wqkv_bf + (size_t)(nt * 16 + l15) * C + ks * 32 + lg * 8);
#pragma unroll
        for (int m = 0; m < 4; ++m)
          acc[j][m] = __builtin_amdgcn_mfma_f32_16x16x32_bf16(af[m], bfr, acc[j][m], 0, 0, 0);
      }
    }
#pragma unroll
    for (int j = 0; j < 5; ++j) {
      int nt = wv + 8 * j;
      if (nt < 36) {
        int cn = nt * 16 + l15;              // qkv column 0..575
        float bias = bqkv[cn];
#pragma unroll
        for (int m = 0; m < 4; ++m) {
#pragma unroll
          for (int r = 0; r < 4; ++r) {
            int row = m * 16 + lg * 4 + r;   // token
            float val = acc[j][m][r] + bias;
            if (cn < 2 * C) {
              qk[row * QK_LD + cn] = (__bf16)val;
            } else {
              int hh = (cn - 2 * C) >> 5, d = (cn - 2 * C) & 31;
              vt[(hh * HD + d) * VT_LD + row] = (__bf16)val;
            }
          }
        }
      }
    }
  }
  __syncthreads();

  // ---- phase 3+4: attention, 24 units = 6 heads x 4 row-quarters ----
  const float scale = 0.17677669529663687f;
#pragma unroll 1
  for (int u = wv; u < 24; u += 8) {
    int h = u >> 2, qt = u & 3;

    f32x4 s[4];
    {
      bf16x8 aq = *(const bf16x8*)(&qk[(qt * 16 + l15) * QK_LD + h * HD + lg * 8]);
#pragma unroll
      for (int ntj = 0; ntj < 4; ++ntj) {
        bf16x8 bk = *(const bf16x8*)(&qk[(ntj * 16 + l15) * QK_LD + C + h * HD + lg * 8]);
        f32x4 z = (f32x4){0.f, 0.f, 0.f, 0.f};
        s[ntj] = __builtin_amdgcn_mfma_f32_16x16x32_bf16(aq, bk, z, 0, 0, 0);
      }
    }
    const float* bh = bias6 + h * PP * PP;
#pragma unroll
    for (int r = 0; r < 4; ++r) {
      int p = qt * 16 + lg * 4 + r;          // query token (row)
      float sv[4];
      float mx = -1e30f;
#pragma unroll
      for (int ntj = 0; ntj < 4; ++ntj) {
        int q = ntj * 16 + l15;              // key token (col)
        float v = s[ntj][r] * scale;
        if (p < PP && q < PP) v += bh[p * PP + q];
        if (q >= PP) v = -1e30f;             // mask pad keys
        sv[ntj] = v;
        mx = fmaxf(mx, v);
      }
#pragma unroll
      for (int d = 1; d < 16; d <<= 1) mx = fmaxf(mx, __shfl_xor(mx, d));
      float ev[4];
      float sum = 0.f;
#pragma unroll
      for (int ntj = 0; ntj < 4; ++ntj) {
        ev[ntj] = __expf(sv[ntj] - mx);
        sum += ev[ntj];
      }
#pragma unroll
      for (int d = 1; d < 16; d <<= 1) sum += __shfl_xor(sum, d);
      float inv = 1.f / sum;
#pragma unroll
      for (int ntj = 0; ntj < 4; ++ntj)
        pr[(wv * 16 + lg * 4 + r) * PR_LD + ntj * 16 + l15] = (__bf16)(ev[ntj] * inv);
    }

    // PV: out[16 rows][32 dims] = probs[16][64] @ v[64][32]
    f32x4 o[2];
    o[0] = (f32x4){0.f, 0.f, 0.f, 0.f};
    o[1] = (f32x4){0.f, 0.f, 0.f, 0.f};
#pragma unroll
    for (int ks = 0; ks < 2; ++ks) {
      bf16x8 ap = *(const bf16x8*)(&pr[(wv * 16 + l15) * PR_LD + ks * 32 + lg * 8]);
#pragma unroll
      for (int ntj = 0; ntj < 2; ++ntj) {
        bf16x8 bv = *(const bf16x8*)(&vt[(h * HD + ntj * 16 + l15) * VT_LD + ks * 32 + lg * 8]);
        o[ntj] = __builtin_amdgcn_mfma_f32_16x16x32_bf16(ap, bv, o[ntj], 0, 0, 0);
      }
    }
#pragma unroll
    for (int ntj = 0; ntj < 2; ++ntj)
#pragma unroll
      for (int r = 0; r < 4; ++r)
        xw[(qt * 16 + lg * 4 + r) * XW_LD + h * HD + ntj * 16 + l15] = (__bf16)o[ntj][r];
  }
  __syncthreads();

  // ---- phase 5: GEMM2  final = attn @ wout^T + b_out, store (b,c,h,w) ----
  {
    int mh  = wv >> 2;            // row half: 0 -> rows 0..31, 1 -> rows 32..63
    int nt0 = (wv & 3) * 3;       // 3 n-tiles per wave
    f32x4 acc[3][2];
#pragma unroll
    for (int j = 0; j < 3; ++j)
#pragma unroll
      for (int mm = 0; mm < 2; ++mm) acc[j][mm] = (f32x4){0.f, 0.f, 0.f, 0.f};

#pragma unroll
    for (int ks = 0; ks < 6; ++ks) {
      bf16x8 af[2];
#pragma unroll
      for (int mm = 0; mm < 2; ++mm)
        af[mm] = *(const bf16x8*)(&xw[((mh * 2 + mm) * 16 + l15) * XW_LD + ks * 32 + lg * 8]);
#pragma unroll
      for (int j = 0; j < 3; ++j) {
        int cn = (nt0 + j) * 16 + l15;
        bf16x8 bfr = *(const bf16x8*)(wout_bf + (size_t)cn * C + ks * 32 + lg * 8);
#pragma unroll
        for (int mm = 0; mm < 2; ++mm)
          acc[j][mm] = __builtin_amdgcn_mfma_f32_16x16x32_bf16(af[mm], bfr, acc[j][mm], 0, 0, 0);
      }
    }
#pragma unroll
    for (int j = 0; j < 3; ++j) {
      int cn = (nt0 + j) * 16 + l15;        // output channel
      float bias = bout[cn];
      float* obase = out + ((size_t)bb * C + cn) * HH * WWID + (size_t)(wy * PW) * WWID + wx * PW;
#pragma unroll
      for (int mm = 0; mm < 2; ++mm) {
#pragma unroll
        for (int r = 0; r < 4; ++r) {
          int row = (mh * 2 + mm) * 16 + lg * 4 + r;   // token
          if (row < PP) {
            int py = row / PW, px = row - py * PW;
            obase[py * WWID + px] = acc[j][mm][r] + bias;
          }
        }
      }
    }
  }
}

extern "C" void kernel_launch(void* const* d_in, const int* in_sizes, int n_in,
                              void* d_out, int out_size, void* d_ws, size_t ws_size,
                              hipStream_t stream) {
  const float* x    = (const float*)d_in[0];
  const float* wqkv = (const float*)d_in[1];
  const float* bqkv = (const float*)d_in[2];
  const float* relp = (const float*)d_in[3];
  const float* wout = (const float*)d_in[4];
  const float* bout = (const float*)d_in[5];
  float* outp = (float*)d_out;

  // ws layout: wqkv_bf16 (221184 B) | wout_bf16 (73728 B) | bias6 f32 (57624 B)
  __bf16* wqkv_bf = (__bf16*)d_ws;
  __bf16* wout_bf = wqkv_bf + (size_t)C3 * C;
  float*  bias6   = (float*)(wout_bf + (size_t)C * C);

  wla_prep<<<dim3(128), dim3(256), 0, stream>>>(wqkv, wout, relp, wqkv_bf, wout_bf, bias6);
  wla_main<<<dim3(NB * 1024), dim3(512), 0, stream>>>(x, wqkv_bf, bqkv, bias6, wout_bf, bout, outp);
}

// Round 2
// 1539.093 us; speedup vs baseline: 1.1561x; 1.1561x over previous
//
#include <hip/hip_runtime.h>
#include <hip/hip_bf16.h>

typedef __bf16 bf16x8 __attribute__((ext_vector_type(8)));
typedef float  f32x4  __attribute__((ext_vector_type(4)));
typedef unsigned short u16x8 __attribute__((ext_vector_type(8)));

#define NB   8
#define C    192
#define C3   576
#define HH   224
#define WWID 224
#define HW   50176
#define PW   7
#define NH   6
#define HD   32
#define PP   49
#define MPAD 64

#define Q_LD  200   // q/k/attnout row stride (bf16): 400 B, dword%32==4, 16B-mult
#define VT_LD 72
#define PR_LD 72

static __device__ __forceinline__ unsigned int pack2bf(float a, float b) {
  union { __bf16 h[2]; unsigned int u; } x;
  x.h[0] = (__bf16)a; x.h[1] = (__bf16)b;
  return x.u;
}

__global__ void wla_prep(const float* __restrict__ wqkv, const float* __restrict__ wout,
                         const float* __restrict__ relpos,
                         __bf16* __restrict__ wqkv_bf, __bf16* __restrict__ wout_bf,
                         float* __restrict__ bias6) {
  const int n1 = C3 * C, n2 = C * C, n3 = NH * PP * PP;
  for (int i = blockIdx.x * blockDim.x + threadIdx.x; i < n1 + n2 + n3;
       i += gridDim.x * blockDim.x) {
    if (i < n1) {
      wqkv_bf[i] = (__bf16)wqkv[i];
    } else if (i < n1 + n2) {
      wout_bf[i - n1] = (__bf16)wout[i - n1];
    } else {
      int e = i - n1 - n2;
      int h = e / (PP * PP), r = e % (PP * PP);
      int p = r / PP, q = r % PP;
      int di = p / PW - q / PW + (PW - 1);
      int dj = p % PW - q % PW + (PW - 1);
      bias6[e] = relpos[(h * (2 * PW - 1) + di) * (2 * PW - 1) + dj];
    }
  }
}

// x (b,c,224,224) f32  ->  xT (b,224,224,c) bf16.  64-pixel x 192-channel tiles.
__global__ __launch_bounds__(256)
void wla_tr(const float* __restrict__ x, __bf16* __restrict__ xT) {
  __shared__ unsigned int tl[C * 33];    // [c][px packed 2/bf16-pair], 132 B/row
  const int t = threadIdx.x;
  const int bidb = blockIdx.x / 784;
  const int tile = blockIdx.x % 784;
  const size_t pix0 = (size_t)tile * 64;

#pragma unroll
  for (int p = 0; p < 12; ++p) {
    int c = p * 16 + (t >> 4);
    int px0 = (t & 15) * 4;
    const float4 v = *(const float4*)(x + ((size_t)(bidb * C + c)) * HW + pix0 + px0);
    tl[c * 33 + (px0 >> 1)]     = pack2bf(v.x, v.y);
    tl[c * 33 + (px0 >> 1) + 1] = pack2bf(v.z, v.w);
  }
  __syncthreads();

  const int px = t >> 2, seg = t & 3;
  const unsigned short* tls = (const unsigned short*)tl;
  __bf16* obase = xT + ((size_t)bidb * HW + pix0 + px) * C;
#pragma unroll
  for (int s = 0; s < 6; ++s) {
    int c0 = seg * 48 + s * 8;
    u16x8 a;
#pragma unroll
    for (int i = 0; i < 8; ++i) a[i] = tls[(c0 + i) * 66 + px];
    *(u16x8*)((unsigned short*)obase + c0) = a;
  }
}

// ---------------- fused per-window kernel, v2: xT input, 2 blocks/CU ----------------
__global__ __launch_bounds__(512, 4)
void wla_main(const __bf16* __restrict__ xT,
              const __bf16* __restrict__ wqkv_bf, const float* __restrict__ bqkv,
              const float* __restrict__ bias6,
              const __bf16* __restrict__ wout_bf, const float* __restrict__ bout,
              float* __restrict__ out) {
  // 25600 + 25600 + 27648 = 78848 B  (<= 81920 -> 2 blocks/CU)
  __shared__ __align__(16) __bf16 qbuf[MPAD * Q_LD];   // q; later probs (pr) per-wave slots
  __shared__ __align__(16) __bf16 kbuf[MPAD * Q_LD];   // k; later attn-out
  __shared__ __align__(16) __bf16 vt[NH * HD * VT_LD]; // v^T: [h*32+d][token]

  const int tid  = threadIdx.x;
  const int lane = tid & 63;
  const int wv   = tid >> 6;
  const int l15  = lane & 15;
  const int lg   = lane >> 4;

  const int blk = blockIdx.x;
  const int bb  = blk >> 10;
  const int wi  = blk & 1023;
  const int wy  = wi >> 5, wx = wi & 31;

  // per-lane A-row pointers for GEMM1 (token = m*16 + l15); pad tokens clamp to pixel 0
  const __bf16* aptr[4];
#pragma unroll
  for (int m = 0; m < 4; ++m) {
    int T = m * 16 + l15;
    int py = T / 7, px = T - py * 7;
    int pix = (wy * PW + py) * WWID + wx * PW + px;
    if (T >= PP) pix = 0;                       // finite dummy rows, never stored
    aptr[m] = xT + ((size_t)bb * HW + pix) * C;
  }

  // ---- GEMM1: qkv = x @ wqkv^T + b  (M=64, N=576, K=192), A direct from global ----
  {
    f32x4 acc[5][4];
#pragma unroll
    for (int j = 0; j < 5; ++j)
#pragma unroll
      for (int m = 0; m < 4; ++m) acc[j][m] = (f32x4){0.f, 0.f, 0.f, 0.f};

#pragma unroll
    for (int ks = 0; ks < 6; ++ks) {
      bf16x8 af[4];
#pragma unroll
      for (int m = 0; m < 4; ++m)
        af[m] = *(const bf16x8*)(aptr[m] + ks * 32 + lg * 8);
#pragma unroll
      for (int j = 0; j < 5; ++j) {
        int nt = wv + 8 * j;  // nt>=36 discarded (reads spill into wout_bf region of ws)
        bf16x8 bfr = *(const bf16x8*)(wqkv_bf + (size_t)(nt * 16 + l15) * C + ks * 32 + lg * 8);
#pragma unroll
        for (int m = 0; m < 4; ++m)
          acc[j][m] = __builtin_amdgcn_mfma_f32_16x16x32_bf16(af[m], bfr, acc[j][m], 0, 0, 0);
      }
    }
#pragma unroll
    for (int j = 0; j < 5; ++j) {
      int nt = wv + 8 * j;
      if (nt < 36) {
        int cn = nt * 16 + l15;
        float bias = bqkv[cn];
#pragma unroll
        for (int m = 0; m < 4; ++m) {
#pragma unroll
          for (int r = 0; r < 4; ++r) {
            int row = m * 16 + lg * 4 + r;
            float val = acc[j][m][r] + bias;
            if (cn < C) {
              qbuf[row * Q_LD + cn] = (__bf16)val;
            } else if (cn < 2 * C) {
              kbuf[row * Q_LD + (cn - C)] = (__bf16)val;
            } else {
              vt[(cn - 2 * C) * VT_LD + row] = (__bf16)val;
            }
          }
        }
      }
    }
  }
  __syncthreads();

  // ---- attention P3a: all QK^T + softmax, probs kept in registers ----
  const float scale = 0.17677669529663687f;
  unsigned int pregs[3][8];   // [unit][ntj*2 + r/2] packed bf16 pairs (r, r+1)
#pragma unroll
  for (int uu = 0; uu < 3; ++uu) {
    int u = uu * 8 + wv;
    int h = u >> 2, qt = u & 3;

    f32x4 s[4];
    {
      bf16x8 aq = *(const bf16x8*)(&qbuf[(qt * 16 + l15) * Q_LD + h * HD + lg * 8]);
#pragma unroll
      for (int ntj = 0; ntj < 4; ++ntj) {
        bf16x8 bk = *(const bf16x8*)(&kbuf[(ntj * 16 + l15) * Q_LD + h * HD + lg * 8]);
        f32x4 z = (f32x4){0.f, 0.f, 0.f, 0.f};
        s[ntj] = __builtin_amdgcn_mfma_f32_16x16x32_bf16(aq, bk, z, 0, 0, 0);
      }
    }
    const float* bh = bias6 + h * PP * PP;
    float pf[4][4];  // [r][ntj]
#pragma unroll
    for (int r = 0; r < 4; ++r) {
      int p = qt * 16 + lg * 4 + r;
      float sv[4];
      float mx = -1e30f;
#pragma unroll
      for (int ntj = 0; ntj < 4; ++ntj) {
        int q = ntj * 16 + l15;
        float v = s[ntj][r] * scale;
        if (p < PP && q < PP) v += bh[p * PP + q];
        if (q >= PP) v = -1e30f;
        sv[ntj] = v;
        mx = fmaxf(mx, v);
      }
#pragma unroll
      for (int d = 1; d < 16; d <<= 1) mx = fmaxf(mx, __shfl_xor(mx, d));
      float ev[4];
      float sum = 0.f;
#pragma unroll
      for (int ntj = 0; ntj < 4; ++ntj) {
        ev[ntj] = __expf(sv[ntj] - mx);
        sum += ev[ntj];
      }
#pragma unroll
      for (int d = 1; d < 16; d <<= 1) sum += __shfl_xor(sum, d);
      float inv = 1.f / sum;
#pragma unroll
      for (int ntj = 0; ntj < 4; ++ntj) pf[r][ntj] = ev[ntj] * inv;
    }
#pragma unroll
    for (int ntj = 0; ntj < 4; ++ntj)
#pragma unroll
      for (int rr = 0; rr < 2; ++rr)
        pregs[uu][ntj * 2 + rr] = pack2bf(pf[rr * 2][ntj], pf[rr * 2 + 1][ntj]);
  }
  __syncthreads();   // q,k now dead -> reuse qbuf for probs, kbuf for attn-out

  // ---- attention P3b: probs -> LDS slot, PV, attn-out into kbuf ----
#pragma unroll
  for (int uu = 0; uu < 3; ++uu) {
    int u = uu * 8 + wv;
    int h = u >> 2, qt = u & 3;
    unsigned short* pr = (unsigned short*)qbuf + wv * 16 * PR_LD;

#pragma unroll
    for (int ntj = 0; ntj < 4; ++ntj)
#pragma unroll
      for (int r = 0; r < 4; ++r) {
        unsigned int pk = pregs[uu][ntj * 2 + (r >> 1)];
        pr[(lg * 4 + r) * PR_LD + ntj * 16 + l15] =
            (unsigned short)(pk >> ((r & 1) * 16));
      }

    f32x4 o[2];
    o[0] = (f32x4){0.f, 0.f, 0.f, 0.f};
    o[1] = (f32x4){0.f, 0.f, 0.f, 0.f};
#pragma unroll
    for (int ks = 0; ks < 2; ++ks) {
      bf16x8 ap = *(const bf16x8*)((const __bf16*)qbuf + wv * 16 * PR_LD + l15 * PR_LD + ks * 32 + lg * 8);
#pragma unroll
      for (int ntj = 0; ntj < 2; ++ntj) {
        bf16x8 bv = *(const bf16x8*)(&vt[(h * HD + ntj * 16 + l15) * VT_LD + ks * 32 + lg * 8]);
        o[ntj] = __builtin_amdgcn_mfma_f32_16x16x32_bf16(ap, bv, o[ntj], 0, 0, 0);
      }
    }
#pragma unroll
    for (int ntj = 0; ntj < 2; ++ntj)
#pragma unroll
      for (int r = 0; r < 4; ++r)
        kbuf[(qt * 16 + lg * 4 + r) * Q_LD + h * HD + ntj * 16 + l15] = (__bf16)o[ntj][r];
  }
  __syncthreads();

  // ---- GEMM2: final = attn @ wout^T + b_out ----
  {
    int mh  = wv >> 2;
    int nt0 = (wv & 3) * 3;
    f32x4 acc[3][2];
#pragma unroll
    for (int j = 0; j < 3; ++j)
#pragma unroll
      for (int mm = 0; mm < 2; ++mm) acc[j][mm] = (f32x4){0.f, 0.f, 0.f, 0.f};

#pragma unroll
    for (int ks = 0; ks < 6; ++ks) {
      bf16x8 af[2];
#pragma unroll
      for (int mm = 0; mm < 2; ++mm)
        af[mm] = *(const bf16x8*)(&kbuf[((mh * 2 + mm) * 16 + l15) * Q_LD + ks * 32 + lg * 8]);
#pragma unroll
      for (int j = 0; j < 3; ++j) {
        int cn = (nt0 + j) * 16 + l15;
        bf16x8 bfr = *(const bf16x8*)(wout_bf + (size_t)cn * C + ks * 32 + lg * 8);
#pragma unroll
        for (int mm = 0; mm < 2; ++mm)
          acc[j][mm] = __builtin_amdgcn_mfma_f32_16x16x32_bf16(af[mm], bfr, acc[j][mm], 0, 0, 0);
      }
    }
#pragma unroll
    for (int j = 0; j < 3; ++j) {
      int cn = (nt0 + j) * 16 + l15;
      float bias = bout[cn];
      float* obase = out + ((size_t)bb * C + cn) * HW + (size_t)(wy * PW) * WWID + wx * PW;
#pragma unroll
      for (int mm = 0; mm < 2; ++mm) {
#pragma unroll
        for (int r = 0; r < 4; ++r) {
          int row = (mh * 2 + mm) * 16 + lg * 4 + r;
          if (row < PP) {
            int py = row / PW, px = row - py * PW;
            obase[py * WWID + px] = acc[j][mm][r] + bias;
          }
        }
      }
    }
  }
}

// ---------------- round-1 kernel kept verbatim as ws-too-small fallback ----------------
#define XW_LD 200
#define QK_LD 392

__global__ __launch_bounds__(512, 2)
void wla_main_v1(const float* __restrict__ x,
                 const __bf16* __restrict__ wqkv_bf, const float* __restrict__ bqkv,
                 const float* __restrict__ bias6,
                 const __bf16* __restrict__ wout_bf, const float* __restrict__ bout,
                 float* __restrict__ out) {
  __shared__ __align__(16) __bf16 xw[MPAD * XW_LD];
  __shared__ __align__(16) __bf16 qk[MPAD * QK_LD];
  __shared__ __align__(16) __bf16 vt[NH * HD * VT_LD];
  __shared__ __align__(16) __bf16 pr[8 * 16 * PR_LD];

  const int tid  = threadIdx.x;
  const int lane = tid & 63;
  const int wv   = tid >> 6;
  const int l15  = lane & 15;
  const int lg   = lane >> 4;

  const int blk = blockIdx.x;
  const int bb  = blk >> 10;
  const int wi  = blk & 1023;
  const int wy  = wi >> 5, wx = wi & 31;

  const float* xbase = x + (size_t)bb * C * HH * WWID + (size_t)(wy * PW) * WWID + wx * PW;

  for (int e = tid; e < C * PP; e += 512) {
    int c = e / PP, pos = e - c * PP;
    int py = pos / PW, px = pos - py * PW;
    xw[pos * XW_LD + c] = (__bf16)xbase[(size_t)c * HH * WWID + py * WWID + px];
  }
  for (int e = tid; e < (MPAD - PP) * C; e += 512) {
    int rr = e / C, c = e - rr * C;
    xw[(PP + rr) * XW_LD + c] = (__bf16)0.f;
  }
  __syncthreads();

  {
    f32x4 acc[5][4];
#pragma unroll
    for (int j = 0; j < 5; ++j)
#pragma unroll
      for (int m = 0; m < 4; ++m) acc[j][m] = (f32x4){0.f, 0.f, 0.f, 0.f};
#pragma unroll
    for (int ks = 0; ks < 6; ++ks) {
      bf16x8 af[4];
#pragma unroll
      for (int m = 0; m < 4; ++m)
        af[m] = *(const bf16x8*)(&xw[(m * 16 + l15) * XW_LD + ks * 32 + lg * 8]);
#pragma unroll
      for (int j = 0; j < 5; ++j) {
        int nt = wv + 8 * j;
        bf16x8 bfr = *(const bf16x8*)(wqkv_bf + (size_t)(nt * 16 + l15) * C + ks * 32 + lg * 8);
#pragma unroll
        for (int m = 0; m < 4; ++m)
          acc[j][m] = __builtin_amdgcn_mfma_f32_16x16x32_bf16(af[m], bfr, acc[j][m], 0, 0, 0);
      }
    }
#pragma unroll
    for (int j = 0; j < 5; ++j) {
      int nt = wv + 8 * j;
      if (nt < 36) {
        int cn = nt * 16 + l15;
        float bias = bqkv[cn];
#pragma unroll
        for (int m = 0; m < 4; ++m) {
#pragma unroll
          for (int r = 0; r < 4; ++r) {
            int row = m * 16 + lg * 4 + r;
            float val = acc[j][m][r] + bias;
            if (cn < 2 * C) {
              qk[row * QK_LD + cn] = (__bf16)val;
            } else {
              int hh = (cn - 2 * C) >> 5, d = (cn - 2 * C) & 31;
              vt[(hh * HD + d) * VT_LD + row] = (__bf16)val;
            }
          }
        }
      }
    }
  }
  __syncthreads();

  const float scale = 0.17677669529663687f;
#pragma unroll 1
  for (int u = wv; u < 24; u += 8) {
    int h = u >> 2, qt = u & 3;
    f32x4 s[4];
    {
      bf16x8 aq = *(const bf16x8*)(&qk[(qt * 16 + l15) * QK_LD + h * HD + lg * 8]);
#pragma unroll
      for (int ntj = 0; ntj < 4; ++ntj) {
        bf16x8 bk = *(const bf16x8*)(&qk[(ntj * 16 + l15) * QK_LD + C + h * HD + lg * 8]);
        f32x4 z = (f32x4){0.f, 0.f, 0.f, 0.f};
        s[ntj] = __builtin_amdgcn_mfma_f32_16x16x32_bf16(aq, bk, z, 0, 0, 0);
      }
    }
    const float* bh = bias6 + h * PP * PP;
#pragma unroll
    for (int r = 0; r < 4; ++r) {
      int p = qt * 16 + lg * 4 + r;
      float sv[4];
      float mx = -1e30f;
#pragma unroll
      for (int ntj = 0; ntj < 4; ++ntj) {
        int q = ntj * 16 + l15;
        float v = s[ntj][r] * scale;
        if (p < PP && q < PP) v += bh[p * PP + q];
        if (q >= PP) v = -1e30f;
        sv[ntj] = v;
        mx = fmaxf(mx, v);
      }
#pragma unroll
      for (int d = 1; d < 16; d <<= 1) mx = fmaxf(mx, __shfl_xor(mx, d));
      float ev[4];
      float sum = 0.f;
#pragma unroll
      for (int ntj = 0; ntj < 4; ++ntj) {
        ev[ntj] = __expf(sv[ntj] - mx);
        sum += ev[ntj];
      }
#pragma unroll
      for (int d = 1; d < 16; d <<= 1) sum += __shfl_xor(sum, d);
      float inv = 1.f / sum;
#pragma unroll
      for (int ntj = 0; ntj < 4; ++ntj)
        pr[(wv * 16 + lg * 4 + r) * PR_LD + ntj * 16 + l15] = (__bf16)(ev[ntj] * inv);
    }
    f32x4 o[2];
    o[0] = (f32x4){0.f, 0.f, 0.f, 0.f};
    o[1] = (f32x4){0.f, 0.f, 0.f, 0.f};
#pragma unroll
    for (int ks = 0; ks < 2; ++ks) {
      bf16x8 ap = *(const bf16x8*)(&pr[(wv * 16 + l15) * PR_LD + ks * 32 + lg * 8]);
#pragma unroll
      for (int ntj = 0; ntj < 2; ++ntj) {
        bf16x8 bv = *(const bf16x8*)(&vt[(h * HD + ntj * 16 + l15) * VT_LD + ks * 32 + lg * 8]);
        o[ntj] = __builtin_amdgcn_mfma_f32_16x16x32_bf16(ap, bv, o[ntj], 0, 0, 0);
      }
    }
#pragma unroll
    for (int ntj = 0; ntj < 2; ++ntj)
#pragma unroll
      for (int r = 0; r < 4; ++r)
        xw[(qt * 16 + lg * 4 + r) * XW_LD + h * HD + ntj * 16 + l15] = (__bf16)o[ntj][r];
  }
  __syncthreads();

  {
    int mh  = wv >> 2;
    int nt0 = (wv & 3) * 3;
    f32x4 acc[3][2];
#pragma unroll
    for (int j = 0; j < 3; ++j)
#pragma unroll
      for (int mm = 0; mm < 2; ++mm) acc[j][mm] = (f32x4){0.f, 0.f, 0.f, 0.f};
#pragma unroll
    for (int ks = 0; ks < 6; ++ks) {
      bf16x8 af[2];
#pragma unroll
      for (int mm = 0; mm < 2; ++mm)
        af[mm] = *(const bf16x8*)(&xw[((mh * 2 + mm) * 16 + l15) * XW_LD + ks * 32 + lg * 8]);
#pragma unroll
      for (int j = 0; j < 3; ++j) {
        int cn = (nt0 + j) * 16 + l15;
        bf16x8 bfr = *(const bf16x8*)(wout_bf + (size_t)cn * C + ks * 32 + lg * 8);
#pragma unroll
        for (int mm = 0; mm < 2; ++mm)
          acc[j][mm] = __builtin_amdgcn_mfma_f32_16x16x32_bf16(af[mm], bfr, acc[j][mm], 0, 0, 0);
      }
    }
#pragma unroll
    for (int j = 0; j < 3; ++j) {
      int cn = (nt0 + j) * 16 + l15;
      float bias = bout[cn];
      float* obase = out + ((size_t)bb * C + cn) * HW + (size_t)(wy * PW) * WWID + wx * PW;
#pragma unroll
      for (int mm = 0; mm < 2; ++mm) {
#pragma unroll
        for (int r = 0; r < 4; ++r) {
          int row = (mh * 2 + mm) * 16 + lg * 4 + r;
          if (row < PP) {
            int py = row / PW, px = row - py * PW;
            obase[py * WWID + px] = acc[j][mm][r] + bias;
          }
        }
      }
    }
  }
}

extern "C" void kernel_launch(void* const* d_in, const int* in_sizes, int n_in,
                              void* d_out, int out_size, void* d_ws, size_t ws_size,
                              hipStream_t stream) {
  const float* x    = (const float*)d_in[0];
  const float* wqkv = (const float*)d_in[1];
  const float* bqkv = (const float*)d_in[2];
  const float* relp = (const float*)d_in[3];
  const float* wout = (const float*)d_in[4];
  const float* bout = (const float*)d_in[5];
  float* outp = (float*)d_out;

  // ws: wqkv_bf (221184 B) | wout_bf (73728 B) | bias6 (57624 B) | pad | xT @ 512 KiB
  __bf16* wqkv_bf = (__bf16*)d_ws;
  __bf16* wout_bf = wqkv_bf + (size_t)C3 * C;
  float*  bias6   = (float*)(wout_bf + (size_t)C * C);

  const size_t XT_OFF = 524288;
  const size_t xt_bytes = (size_t)NB * HW * C * 2;   // ~147 MB

  wla_prep<<<dim3(128), dim3(256), 0, stream>>>(wqkv, wout, relp, wqkv_bf, wout_bf, bias6);

  if (ws_size >= XT_OFF + xt_bytes) {
    __bf16* xT = (__bf16*)((char*)d_ws + XT_OFF);
    wla_tr<<<dim3(NB * 784), dim3(256), 0, stream>>>(x, xT);
    wla_main<<<dim3(NB * 1024), dim3(512), 0, stream>>>(xT, wqkv_bf, bqkv, bias6,
                                                        wout_bf, bout, outp);
  } else {
    wla_main_v1<<<dim3(NB * 1024), dim3(512), 0, stream>>>(x, wqkv_bf, bqkv, bias6,
                                                           wout_bf, bout, outp);
  }
}